// Round 7
// baseline (1600.932 us; speedup 1.0000x reference)
//
#include <hip/hip_runtime.h>
#include <hip/hip_bf16.h>

#define N_USERS   50000
#define N_ITEMS   100000
#define N_NODES   150000
#define DIM       64
#define N_INTENTS 128
#define N_EDGES   3000000
#define BSHIFT    2                        // 4 rows per bucket
#define NBUCK     (N_NODES >> BSHIFT)      // 37500 (exact)

static __device__ __forceinline__ float wsum64(float v){
#pragma unroll
  for (int m = 32; m >= 1; m >>= 1) v += __shfl_xor(v, m, 64);
  return v;
}
static __device__ __forceinline__ float wmax64(float v){
#pragma unroll
  for (int m = 32; m >= 1; m >>= 1) v = fmaxf(v, __shfl_xor(v, m, 64));
  return v;
}

// ---- DPP 16-lane row reduction (full-rate VALU)
template<int CTRL>
static __device__ __forceinline__ float dpp_ror_add(float x){
  int t = __builtin_amdgcn_update_dpp(0, __builtin_bit_cast(int, x),
                                      CTRL, 0xF, 0xF, true);
  return x + __builtin_bit_cast(float, t);
}
static __device__ __forceinline__ float row16_allsum(float x){
  x = dpp_ror_add<0x128>(x);  // row_ror:8
  x = dpp_ror_add<0x124>(x);  // row_ror:4
  x = dpp_ror_add<0x122>(x);  // row_ror:2
  x = dpp_ror_add<0x121>(x);  // row_ror:1
  return x;
}

// bf16 pack/unpack
static __device__ __forceinline__ unsigned short f2bf(float x){
  __hip_bfloat16 h = __float2bfloat16(x);
  return __builtin_bit_cast(unsigned short, h);
}
static __device__ __forceinline__ float bf_lo(unsigned int v){
  return __builtin_bit_cast(float, v << 16);
}
static __device__ __forceinline__ float bf_hi(unsigned int v){
  return __builtin_bit_cast(float, v & 0xFFFF0000u);
}

// emb = concat(user_emb, item_emb); acc(=d_out) = emb; embb = bf16(emb)
__global__ void k_init(const float* __restrict__ ue, const float* __restrict__ ie,
                       float* __restrict__ emb, float* __restrict__ acc,
                       unsigned short* __restrict__ embb){
  int i = blockIdx.x * 256 + threadIdx.x;
  if (i >= N_NODES * DIM) return;
  float v = (i < N_USERS * DIM) ? ue[i] : ie[i - N_USERS * DIM];
  emb[i] = v; acc[i] = v; embb[i] = f2bf(v);
}

__global__ void k_deg(const int* __restrict__ h, int* __restrict__ deg){
  int e = blockIdx.x * 256 + threadIdx.x;
  if (e < N_EDGES) atomicAdd(&deg[h[e]], 1);
}

__global__ void k_scan1(const int* __restrict__ deg, int* __restrict__ tmp,
                        int* __restrict__ aux){
  __shared__ int s[256];
  int t = threadIdx.x, i = blockIdx.x * 256 + t;
  int v = (i < N_NODES) ? deg[i] : 0;
  s[t] = v; __syncthreads();
  for (int off = 1; off < 256; off <<= 1){
    int x = (t >= off) ? s[t - off] : 0;
    __syncthreads();
    s[t] += x;
    __syncthreads();
  }
  if (i < N_NODES) tmp[i] = s[t];
  if (t == 255) aux[blockIdx.x] = s[255];
}

__global__ __launch_bounds__(1024) void k_scan2(int* __restrict__ aux, int n){
  __shared__ int s[1024];
  int t = threadIdx.x;
  int v = (t < n) ? aux[t] : 0;
  s[t] = v; __syncthreads();
  for (int off = 1; off < 1024; off <<= 1){
    int x = (t >= off) ? s[t - off] : 0;
    __syncthreads();
    s[t] += x;
    __syncthreads();
  }
  if (t < n) aux[t] = s[t] - v;   // exclusive
}

__global__ void k_rowptr(const int* __restrict__ tmp, const int* __restrict__ deg,
                         const int* __restrict__ aux, int* __restrict__ rp,
                         float* __restrict__ dis, int* __restrict__ curb){
  int i = blockIdx.x * 256 + threadIdx.x;
  if (i < N_NODES){
    int v = aux[i >> 8] + tmp[i] - deg[i];
    rp[i] = v;
    int d = deg[i];
    dis[i] = (d > 0) ? (1.f / sqrtf((float)d)) : 0.f;
    if ((i & 3) == 0) curb[i >> BSHIFT] = v;  // bucket append cursor = rp[4b]
  }
  if (i == 0) rp[N_NODES] = N_EDGES;
}

// Scatter pass 1: append packed (t<<2)|(h&3) to 4-row bucket (4B/entry).
// 37.5k counters (~80 hits each: negligible same-address atomic serial);
// frontier ~2.4MB merges in L2.
__global__ void k_scat1(const int* __restrict__ h, const int* __restrict__ t,
                        int* __restrict__ curb, unsigned int* __restrict__ stg){
  int e = blockIdx.x * 256 + threadIdx.x;
  if (e >= N_EDGES) return;
  int hh = h[e];
  int pos = atomicAdd(&curb[hh >> BSHIFT], 1);
  stg[pos] = ((unsigned)t[e] << 2) | (unsigned)(hh & 3);
}

// Scatter pass 2: one wave per bucket, ZERO atomics. 4 row-cursors in
// registers; per 64-edge chunk, rank within row via ballot+popcount.
// Each bucket's t_csr span is written by exactly one wave -> full L2 merge.
__global__ void k_scat2(const int* __restrict__ rp, const unsigned int* __restrict__ stg,
                        int* __restrict__ t_csr){
  int b = (blockIdx.x * 256 + threadIdx.x) >> 6;
  int lane = threadIdx.x & 63;
  if (b >= NBUCK) return;
  int s  = rp[b * 4];
  int c0 = s, c1 = rp[b * 4 + 1], c2 = rp[b * 4 + 2], c3 = rp[b * 4 + 3];
  int e  = rp[b * 4 + 4];
  unsigned long long below = (1ULL << lane) - 1ULL;
  for (int base = s; base < e; base += 64){
    int i = base + lane;
    bool act = (i < e);
    unsigned int v = act ? stg[i] : 0u;
    int hl = v & 3;
    int tt = v >> 2;
    unsigned long long m0 = __ballot(act && hl == 0);
    unsigned long long m1 = __ballot(act && hl == 1);
    unsigned long long m2 = __ballot(act && hl == 2);
    unsigned long long m3 = __ballot(act && hl == 3);
    int p0 = c0 + __popcll(m0 & below);
    int p1 = c1 + __popcll(m1 & below);
    int p2 = c2 + __popcll(m2 & below);
    int p3 = c3 + __popcll(m3 & below);
    int pos = (hl == 0) ? p0 : (hl == 1) ? p1 : (hl == 2) ? p2 : p3;
    if (act) t_csr[pos] = tt;
    c0 += __popcll(m0); c1 += __popcll(m1);
    c2 += __popcll(m2); c3 += __popcll(m3);
  }
}

// gnn[n] = dis[n] * sum_e dis[t_e] * emb[t_e], gathering bf16 embb (128B/edge)
__global__ void k_spmm_gnn(const int* __restrict__ rp, const int* __restrict__ t_csr,
                           const float* __restrict__ dis,
                           const uint2* __restrict__ embb2,
                           float* __restrict__ gnn, unsigned short* __restrict__ hgig_s){
  int w = (blockIdx.x * 256 + threadIdx.x) >> 6;
  int lane = threadIdx.x & 63;
  if (w >= N_NODES) return;
  int slot = lane >> 4, sub = lane & 15;
  int s = rp[w], e = rp[w + 1];
  float4 a = make_float4(0.f, 0.f, 0.f, 0.f);
  for (int i = s + slot; i < e; i += 4){
    int t = t_csr[i];
    float wt = dis[t];
    uint2 ev = embb2[t * 16 + sub];
    a.x = fmaf(wt, bf_lo(ev.x), a.x);
    a.y = fmaf(wt, bf_hi(ev.x), a.y);
    a.z = fmaf(wt, bf_lo(ev.y), a.z);
    a.w = fmaf(wt, bf_hi(ev.y), a.w);
  }
#pragma unroll
  for (int m = 16; m <= 32; m <<= 1){
    a.x += __shfl_xor(a.x, m, 64);
    a.y += __shfl_xor(a.y, m, 64);
    a.z += __shfl_xor(a.z, m, 64);
    a.w += __shfl_xor(a.w, m, 64);
  }
  float dw = dis[w];
  float4 gv = make_float4(dw * a.x, dw * a.y, dw * a.z, dw * a.w);
  float sq = gv.x * gv.x + gv.y * gv.y + gv.z * gv.z + gv.w * gv.w;
  float nrm = row16_allsum(sq);
  float invn = 1.f / fmaxf(sqrtf(nrm), 1e-8f);
  if (slot == 0){
    ((float4*)gnn)[w * 16 + sub] = gv;
    int base = (w * DIM + 4 * sub) * 2;
    hgig_s[base]     = f2bf(gv.x * invn);
    hgig_s[base + 2] = f2bf(gv.y * invn);
    hgig_s[base + 4] = f2bf(gv.z * invn);
    hgig_s[base + 6] = f2bf(gv.w * invn);
  }
}

// out(bf16)[n] = softmax(emb[n] @ W) @ W^T ; + L2-normalize -> high half of hgig
__global__ __launch_bounds__(256) void k_intent(const float* __restrict__ W,
                                                const float* __restrict__ emb,
                                                unsigned short* __restrict__ out_bf,
                                                unsigned short* __restrict__ hgig_s,
                                                int base_node, int count){
  __shared__ float Wl[DIM * 129];
  __shared__ float el[4][DIM];
  __shared__ float pl[4][N_INTENTS];
  int tid = threadIdx.x;
  for (int i = tid; i < DIM * N_INTENTS; i += 256){
    int d = i >> 7, j = i & 127;
    Wl[d * 129 + j] = W[i];
  }
  __syncthreads();
  int wv = tid >> 6, lane = tid & 63;
  for (int base = blockIdx.x * 4; base < count; base += gridDim.x * 4){
    int n = base + wv;
    bool act = (n < count);
    if (act) el[wv][lane] = emb[(base_node + n) * DIM + lane];
    __syncthreads();
    float L0 = 0.f, L1 = 0.f;
    if (act){
#pragma unroll
      for (int d = 0; d < DIM; d++){
        float e = el[wv][d];
        L0 = fmaf(e, Wl[d * 129 + lane], L0);
        L1 = fmaf(e, Wl[d * 129 + lane + 64], L1);
      }
    }
    float m = wmax64(fmaxf(L0, L1));
    float p0 = __expf(L0 - m), p1 = __expf(L1 - m);
    float inv = 1.f / wsum64(p0 + p1);
    if (act){ pl[wv][lane] = p0; pl[wv][lane + 64] = p1; }
    __syncthreads();
    if (act){
      float o = 0.f;
#pragma unroll
      for (int j = 0; j < N_INTENTS; j++)
        o = fmaf(pl[wv][j], Wl[lane * 129 + j], o);
      float v = o * inv;
      int idx = (base_node + n) * DIM + lane;
      out_bf[idx] = f2bf(v);
      float nrm = wsum64(v * v);
      float invn = 1.f / fmaxf(sqrtf(nrm), 1e-8f);
      hgig_s[idx * 2 + 1] = f2bf(v * invn);
    }
    __syncthreads();
  }
}

// Fused adaptive passes + residual + acc + bf16 emb for next layer.
__global__ void k_adafuse(const int* __restrict__ rp, const int* __restrict__ t_csr,
                          const uint4* __restrict__ hgig4,
                          const uint2* __restrict__ inte_bf2,
                          const uint2* __restrict__ embb2,
                          const float* __restrict__ emb,
                          float* __restrict__ gnn_io, float* __restrict__ acc,
                          uint2* __restrict__ embb_next2){
  int w = (blockIdx.x * 256 + threadIdx.x) >> 6;
  int lane = threadIdx.x & 63;
  if (w >= N_NODES) return;
  int slot = lane >> 4, sub = lane & 15;
  uint4 hp = hgig4[w * 16 + sub];
  float hg0 = bf_lo(hp.x), hg1 = bf_lo(hp.y), hg2 = bf_lo(hp.z), hg3 = bf_lo(hp.w);
  float hi0 = bf_hi(hp.x), hi1 = bf_hi(hp.y), hi2 = bf_hi(hp.z), hi3 = bf_hi(hp.w);
  int s = rp[w], e = rp[w + 1];
  float4 s1 = make_float4(0.f, 0.f, 0.f, 0.f);
  float4 s2 = make_float4(0.f, 0.f, 0.f, 0.f);
  float r1 = 0.f, r2 = 0.f;
  for (int i = s + slot; i < e; i += 4){
    int t = t_csr[i];
    uint4 tp = hgig4[t * 16 + sub];
    uint2 ev = embb2[t * 16 + sub];
    float p = hg0 * bf_lo(tp.x) + hg1 * bf_lo(tp.y)
            + hg2 * bf_lo(tp.z) + hg3 * bf_lo(tp.w);
    float q = hi0 * bf_hi(tp.x) + hi1 * bf_hi(tp.y)
            + hi2 * bf_hi(tp.z) + hi3 * bf_hi(tp.w);
    p = row16_allsum(p);
    q = row16_allsum(q);
    float a1 = fmaf(p, 0.5f, 0.5f);
    float a2 = fmaf(q, 0.5f, 0.5f);
    r1 += a1; r2 += a2;
    float v0 = bf_lo(ev.x), v1 = bf_hi(ev.x), v2 = bf_lo(ev.y), v3 = bf_hi(ev.y);
    s1.x = fmaf(a1, v0, s1.x); s1.y = fmaf(a1, v1, s1.y);
    s1.z = fmaf(a1, v2, s1.z); s1.w = fmaf(a1, v3, s1.w);
    s2.x = fmaf(a2, v0, s2.x); s2.y = fmaf(a2, v1, s2.y);
    s2.z = fmaf(a2, v2, s2.z); s2.w = fmaf(a2, v3, s2.w);
  }
#pragma unroll
  for (int m = 16; m <= 32; m <<= 1){
    s1.x += __shfl_xor(s1.x, m, 64); s1.y += __shfl_xor(s1.y, m, 64);
    s1.z += __shfl_xor(s1.z, m, 64); s1.w += __shfl_xor(s1.w, m, 64);
    s2.x += __shfl_xor(s2.x, m, 64); s2.y += __shfl_xor(s2.y, m, 64);
    s2.z += __shfl_xor(s2.z, m, 64); s2.w += __shfl_xor(s2.w, m, 64);
    r1   += __shfl_xor(r1,   m, 64); r2   += __shfl_xor(r2,   m, 64);
  }
  float d1 = (r1 > 0.f) ? 1.f / r1 : 0.f;
  float d2 = (r2 > 0.f) ? 1.f / r2 : 0.f;
  if (slot == 0){
    int idx4 = w * 16 + sub;
    float4 g = ((float4*)gnn_io)[idx4];
    uint2 it = inte_bf2[idx4];
    float4 em = ((const float4*)emb)[idx4];
    float4 nv;
    nv.x = g.x + bf_lo(it.x) + em.x + d1 * s1.x + d2 * s2.x;
    nv.y = g.y + bf_hi(it.x) + em.y + d1 * s1.y + d2 * s2.y;
    nv.z = g.z + bf_lo(it.y) + em.z + d1 * s1.z + d2 * s2.z;
    nv.w = g.w + bf_hi(it.y) + em.w + d1 * s1.w + d2 * s2.w;
    ((float4*)gnn_io)[idx4] = nv;
    float4 ac = ((float4*)acc)[idx4];
    ac.x += nv.x; ac.y += nv.y; ac.z += nv.z; ac.w += nv.w;
    ((float4*)acc)[idx4] = ac;
    uint2 ob;
    ob.x = (unsigned)f2bf(nv.x) | ((unsigned)f2bf(nv.y) << 16);
    ob.y = (unsigned)f2bf(nv.z) | ((unsigned)f2bf(nv.w) << 16);
    embb_next2[idx4] = ob;   // bf16 emb for next layer (other buffer: no race)
  }
}

extern "C" void kernel_launch(void* const* d_in, const int* in_sizes, int n_in,
                              void* d_out, int out_size, void* d_ws, size_t ws_size,
                              hipStream_t stream){
  const float* ue = (const float*)d_in[0];
  const float* ie = (const float*)d_in[1];
  const float* wu = (const float*)d_in[2];
  const float* wi = (const float*)d_in[3];
  const int* all_h = (const int*)d_in[4];
  const int* all_t = (const int*)d_in[5];
  float* acc = (float*)d_out;

  char* p = (char*)d_ws;
  auto take = [&](size_t bytes)->char*{
    char* r = p; p += (bytes + 255) & ~size_t(255); return r;
  };
  float*  embA  = (float*)take(sizeof(float) * N_NODES * DIM);
  float*  embB  = (float*)take(sizeof(float) * N_NODES * DIM);
  unsigned int* hgig = (unsigned int*)take(sizeof(unsigned int) * N_NODES * DIM);
  unsigned short* inte_bf = (unsigned short*)take(sizeof(short) * N_NODES * DIM);
  unsigned short* embbA   = (unsigned short*)take(sizeof(short) * N_NODES * DIM);
  unsigned short* embbB   = (unsigned short*)take(sizeof(short) * N_NODES * DIM);
  int*    t_csr = (int*)take(sizeof(int) * N_EDGES);
  float*  dis   = (float*)take(sizeof(float) * N_NODES);
  int*    deg   = (int*)take(sizeof(int) * N_NODES);
  int*    tmp   = (int*)take(sizeof(int) * N_NODES);
  int*    aux   = (int*)take(sizeof(int) * 1024);
  int*    rp    = (int*)take(sizeof(int) * (N_NODES + 1));
  int*    curb  = (int*)take(sizeof(int) * NBUCK);
  if ((size_t)(p - (char*)d_ws) > ws_size) return;
  // staging (12 MB) aliases hgig (38.4 MB): only live before the layer loop
  unsigned int* stg = hgig;

  const int ELEM_B  = (N_NODES * DIM + 255) / 256;
  const int NODEW_B = (N_NODES * 64 + 255) / 256;
  const int EDGE_B  = (N_EDGES + 255) / 256;
  const int NODE_B  = (N_NODES + 255) / 256;
  const int BUCKW_B = (NBUCK * 64 + 255) / 256;

  hipMemsetAsync(deg, 0, sizeof(int) * N_NODES, stream);
  k_init<<<ELEM_B, 256, 0, stream>>>(ue, ie, embA, acc, embbA);
  k_deg<<<EDGE_B, 256, 0, stream>>>(all_h, deg);
  k_scan1<<<NODE_B, 256, 0, stream>>>(deg, tmp, aux);
  k_scan2<<<1, 1024, 0, stream>>>(aux, NODE_B);
  k_rowptr<<<NODE_B, 256, 0, stream>>>(tmp, deg, aux, rp, dis, curb);
  k_scat1<<<EDGE_B, 256, 0, stream>>>(all_h, all_t, curb, stg);
  k_scat2<<<BUCKW_B, 256, 0, stream>>>(rp, stg, t_csr);

  float* eA = embA;
  float* eB = embB;
  unsigned short* ebA = embbA;  // bf16 of current emb
  unsigned short* ebB = embbB;
  for (int layer = 0; layer < 2; layer++){
    k_spmm_gnn<<<NODEW_B, 256, 0, stream>>>(rp, t_csr, dis, (const uint2*)ebA,
                                            eB, (unsigned short*)hgig);
    k_intent<<<(N_USERS + 3) / 4, 256, 0, stream>>>(wu, eA, inte_bf,
                                                    (unsigned short*)hgig, 0, N_USERS);
    k_intent<<<(N_ITEMS + 3) / 4, 256, 0, stream>>>(wi, eA, inte_bf,
                                                    (unsigned short*)hgig, N_USERS, N_ITEMS);
    k_adafuse<<<NODEW_B, 256, 0, stream>>>(rp, t_csr, (const uint4*)hgig,
                                           (const uint2*)inte_bf, (const uint2*)ebA,
                                           eA, eB, acc, (uint2*)ebB);
    float* t = eA; eA = eB; eB = t;
    unsigned short* tb = ebA; ebA = ebB; ebB = tb;
  }
}

// Round 8
// 1441.911 us; speedup vs baseline: 1.1103x; 1.1103x over previous
//
#include <hip/hip_runtime.h>
#include <hip/hip_bf16.h>

#define N_USERS   50000
#define N_ITEMS   100000
#define N_NODES   150000
#define DIM       64
#define N_INTENTS 128
#define N_EDGES   3000000
#define PSHIFT    9                         // 512 rows per partition
#define PROWS     (1 << PSHIFT)
#define NPART     ((N_NODES + PROWS - 1) >> PSHIFT)   // 293
#define CHUNK     16384                     // edges per binning block
#define NCHB      ((N_EDGES + CHUNK - 1) / CHUNK)     // 184

static __device__ __forceinline__ float wsum64(float v){
#pragma unroll
  for (int m = 32; m >= 1; m >>= 1) v += __shfl_xor(v, m, 64);
  return v;
}
static __device__ __forceinline__ float wmax64(float v){
#pragma unroll
  for (int m = 32; m >= 1; m >>= 1) v = fmaxf(v, __shfl_xor(v, m, 64));
  return v;
}

// ---- DPP 16-lane row reduction (full-rate VALU)
template<int CTRL>
static __device__ __forceinline__ float dpp_ror_add(float x){
  int t = __builtin_amdgcn_update_dpp(0, __builtin_bit_cast(int, x),
                                      CTRL, 0xF, 0xF, true);
  return x + __builtin_bit_cast(float, t);
}
static __device__ __forceinline__ float row16_allsum(float x){
  x = dpp_ror_add<0x128>(x);  // row_ror:8
  x = dpp_ror_add<0x124>(x);  // row_ror:4
  x = dpp_ror_add<0x122>(x);  // row_ror:2
  x = dpp_ror_add<0x121>(x);  // row_ror:1
  return x;
}

// bf16 pack/unpack
static __device__ __forceinline__ unsigned short f2bf(float x){
  __hip_bfloat16 h = __float2bfloat16(x);
  return __builtin_bit_cast(unsigned short, h);
}
static __device__ __forceinline__ float bf_lo(unsigned int v){
  return __builtin_bit_cast(float, v << 16);
}
static __device__ __forceinline__ float bf_hi(unsigned int v){
  return __builtin_bit_cast(float, v & 0xFFFF0000u);
}

// emb = concat(user_emb, item_emb); acc(=d_out) = emb; embb = bf16(emb)
__global__ void k_init(const float* __restrict__ ue, const float* __restrict__ ie,
                       float* __restrict__ emb, float* __restrict__ acc,
                       unsigned short* __restrict__ embb){
  int i = blockIdx.x * 256 + threadIdx.x;
  if (i >= N_NODES * DIM) return;
  float v = (i < N_USERS * DIM) ? ue[i] : ie[i - N_USERS * DIM];
  emb[i] = v; acc[i] = v; embb[i] = f2bf(v);
}

__global__ void k_deg(const int* __restrict__ h, int* __restrict__ deg){
  int e = blockIdx.x * 256 + threadIdx.x;
  if (e < N_EDGES) atomicAdd(&deg[h[e]], 1);
}

__global__ void k_scan1(const int* __restrict__ deg, int* __restrict__ tmp,
                        int* __restrict__ aux){
  __shared__ int s[256];
  int t = threadIdx.x, i = blockIdx.x * 256 + t;
  int v = (i < N_NODES) ? deg[i] : 0;
  s[t] = v; __syncthreads();
  for (int off = 1; off < 256; off <<= 1){
    int x = (t >= off) ? s[t - off] : 0;
    __syncthreads();
    s[t] += x;
    __syncthreads();
  }
  if (i < N_NODES) tmp[i] = s[t];
  if (t == 255) aux[blockIdx.x] = s[255];
}

__global__ __launch_bounds__(1024) void k_scan2(int* __restrict__ aux, int n){
  __shared__ int s[1024];
  int t = threadIdx.x;
  int v = (t < n) ? aux[t] : 0;
  s[t] = v; __syncthreads();
  for (int off = 1; off < 1024; off <<= 1){
    int x = (t >= off) ? s[t - off] : 0;
    __syncthreads();
    s[t] += x;
    __syncthreads();
  }
  if (t < n) aux[t] = s[t] - v;   // exclusive
}

__global__ void k_rowptr(const int* __restrict__ tmp, const int* __restrict__ deg,
                         const int* __restrict__ aux, int* __restrict__ rp,
                         float* __restrict__ dis, int* __restrict__ gcur){
  int i = blockIdx.x * 256 + threadIdx.x;
  if (i < N_NODES){
    int v = aux[i >> 8] + tmp[i] - deg[i];
    rp[i] = v;
    int d = deg[i];
    dis[i] = (d > 0) ? (1.f / sqrtf((float)d)) : 0.f;
    if ((i & (PROWS - 1)) == 0) gcur[i >> PSHIFT] = v;  // partition append cursor
  }
  if (i == 0) rp[N_NODES] = N_EDGES;
}

// Counting-sort pass 1: per-block LDS histogram over 293 partitions, ONE
// global reservation per (block,partition), then scatter into block-exclusive
// contiguous runs. No cache line is written by more than ~1 block (r5/r7
// lesson: cross-XCD line sharing = 16x write amp; this removes sharing).
__global__ __launch_bounds__(256) void k_part1(const int* __restrict__ h,
                                               const int* __restrict__ t,
                                               int* __restrict__ gcur,
                                               unsigned int* __restrict__ stg){
  __shared__ int hist[NPART];
  __shared__ int base[NPART];
  __shared__ int cnt2[NPART];
  int tid = threadIdx.x;
  int s = blockIdx.x * CHUNK;
  int e = min(s + CHUNK, N_EDGES);
  for (int p = tid; p < NPART; p += 256){ hist[p] = 0; cnt2[p] = 0; }
  __syncthreads();
  for (int i = s + tid; i < e; i += 256)
    atomicAdd(&hist[h[i] >> PSHIFT], 1);
  __syncthreads();
  for (int p = tid; p < NPART; p += 256){
    int c = hist[p];
    base[p] = c ? atomicAdd(&gcur[p], c) : 0;
  }
  __syncthreads();
  for (int i = s + tid; i < e; i += 256){
    int hh = h[i];
    int part = hh >> PSHIFT;
    int pos = base[part] + atomicAdd(&cnt2[part], 1);
    stg[pos] = ((unsigned)t[i] << PSHIFT) | (unsigned)(hh & (PROWS - 1));
  }
}

// Counting-sort pass 2: one block per partition; LDS row cursors; each
// partition's ~40KB t_csr span written by exactly one WG -> full L2 merge.
__global__ __launch_bounds__(256) void k_part2(const int* __restrict__ rp,
                                               const unsigned int* __restrict__ stg,
                                               int* __restrict__ t_csr){
  __shared__ int cur[PROWS];
  int b = blockIdx.x, tid = threadIdx.x;
  int row0 = b << PSHIFT;
  int rows = min(PROWS, N_NODES - row0);
  for (int i = tid; i < rows; i += 256) cur[i] = rp[row0 + i];
  __syncthreads();
  int s = rp[row0], e = rp[row0 + rows];
  for (int i = s + tid; i < e; i += 256){
    unsigned int v = stg[i];
    int pos = atomicAdd(&cur[v & (PROWS - 1)], 1);
    t_csr[pos] = (int)(v >> PSHIFT);
  }
}

// gnn[n] = dis[n] * sum_e dis[t_e] * emb[t_e], gathering bf16 embb (128B/edge)
__global__ void k_spmm_gnn(const int* __restrict__ rp, const int* __restrict__ t_csr,
                           const float* __restrict__ dis,
                           const uint2* __restrict__ embb2,
                           float* __restrict__ gnn, unsigned short* __restrict__ hgig_s){
  int w = (blockIdx.x * 256 + threadIdx.x) >> 6;
  int lane = threadIdx.x & 63;
  if (w >= N_NODES) return;
  int slot = lane >> 4, sub = lane & 15;
  int s = rp[w], e = rp[w + 1];
  float4 a = make_float4(0.f, 0.f, 0.f, 0.f);
  for (int i = s + slot; i < e; i += 4){
    int t = t_csr[i];
    float wt = dis[t];
    uint2 ev = embb2[t * 16 + sub];
    a.x = fmaf(wt, bf_lo(ev.x), a.x);
    a.y = fmaf(wt, bf_hi(ev.x), a.y);
    a.z = fmaf(wt, bf_lo(ev.y), a.z);
    a.w = fmaf(wt, bf_hi(ev.y), a.w);
  }
#pragma unroll
  for (int m = 16; m <= 32; m <<= 1){
    a.x += __shfl_xor(a.x, m, 64);
    a.y += __shfl_xor(a.y, m, 64);
    a.z += __shfl_xor(a.z, m, 64);
    a.w += __shfl_xor(a.w, m, 64);
  }
  float dw = dis[w];
  float4 gv = make_float4(dw * a.x, dw * a.y, dw * a.z, dw * a.w);
  float sq = gv.x * gv.x + gv.y * gv.y + gv.z * gv.z + gv.w * gv.w;
  float nrm = row16_allsum(sq);
  float invn = 1.f / fmaxf(sqrtf(nrm), 1e-8f);
  if (slot == 0){
    ((float4*)gnn)[w * 16 + sub] = gv;
    int base = (w * DIM + 4 * sub) * 2;
    hgig_s[base]     = f2bf(gv.x * invn);
    hgig_s[base + 2] = f2bf(gv.y * invn);
    hgig_s[base + 4] = f2bf(gv.z * invn);
    hgig_s[base + 6] = f2bf(gv.w * invn);
  }
}

// out(bf16)[n] = softmax(emb[n] @ W) @ W^T ; + L2-normalize -> high half of hgig
__global__ __launch_bounds__(256) void k_intent(const float* __restrict__ W,
                                                const float* __restrict__ emb,
                                                unsigned short* __restrict__ out_bf,
                                                unsigned short* __restrict__ hgig_s,
                                                int base_node, int count){
  __shared__ float Wl[DIM * 129];
  __shared__ float el[4][DIM];
  __shared__ float pl[4][N_INTENTS];
  int tid = threadIdx.x;
  for (int i = tid; i < DIM * N_INTENTS; i += 256){
    int d = i >> 7, j = i & 127;
    Wl[d * 129 + j] = W[i];
  }
  __syncthreads();
  int wv = tid >> 6, lane = tid & 63;
  for (int base = blockIdx.x * 4; base < count; base += gridDim.x * 4){
    int n = base + wv;
    bool act = (n < count);
    if (act) el[wv][lane] = emb[(base_node + n) * DIM + lane];
    __syncthreads();
    float L0 = 0.f, L1 = 0.f;
    if (act){
#pragma unroll
      for (int d = 0; d < DIM; d++){
        float e = el[wv][d];
        L0 = fmaf(e, Wl[d * 129 + lane], L0);
        L1 = fmaf(e, Wl[d * 129 + lane + 64], L1);
      }
    }
    float m = wmax64(fmaxf(L0, L1));
    float p0 = __expf(L0 - m), p1 = __expf(L1 - m);
    float inv = 1.f / wsum64(p0 + p1);
    if (act){ pl[wv][lane] = p0; pl[wv][lane + 64] = p1; }
    __syncthreads();
    if (act){
      float o = 0.f;
#pragma unroll
      for (int j = 0; j < N_INTENTS; j++)
        o = fmaf(pl[wv][j], Wl[lane * 129 + j], o);
      float v = o * inv;
      int idx = (base_node + n) * DIM + lane;
      out_bf[idx] = f2bf(v);
      float nrm = wsum64(v * v);
      float invn = 1.f / fmaxf(sqrtf(nrm), 1e-8f);
      hgig_s[idx * 2 + 1] = f2bf(v * invn);
    }
    __syncthreads();
  }
}

// Fused adaptive passes + residual + acc + bf16 emb for next layer.
__global__ void k_adafuse(const int* __restrict__ rp, const int* __restrict__ t_csr,
                          const uint4* __restrict__ hgig4,
                          const uint2* __restrict__ inte_bf2,
                          const uint2* __restrict__ embb2,
                          const float* __restrict__ emb,
                          float* __restrict__ gnn_io, float* __restrict__ acc,
                          uint2* __restrict__ embb_next2){
  int w = (blockIdx.x * 256 + threadIdx.x) >> 6;
  int lane = threadIdx.x & 63;
  if (w >= N_NODES) return;
  int slot = lane >> 4, sub = lane & 15;
  uint4 hp = hgig4[w * 16 + sub];
  float hg0 = bf_lo(hp.x), hg1 = bf_lo(hp.y), hg2 = bf_lo(hp.z), hg3 = bf_lo(hp.w);
  float hi0 = bf_hi(hp.x), hi1 = bf_hi(hp.y), hi2 = bf_hi(hp.z), hi3 = bf_hi(hp.w);
  int s = rp[w], e = rp[w + 1];
  float4 s1 = make_float4(0.f, 0.f, 0.f, 0.f);
  float4 s2 = make_float4(0.f, 0.f, 0.f, 0.f);
  float r1 = 0.f, r2 = 0.f;
  for (int i = s + slot; i < e; i += 4){
    int t = t_csr[i];
    uint4 tp = hgig4[t * 16 + sub];
    uint2 ev = embb2[t * 16 + sub];
    float p = hg0 * bf_lo(tp.x) + hg1 * bf_lo(tp.y)
            + hg2 * bf_lo(tp.z) + hg3 * bf_lo(tp.w);
    float q = hi0 * bf_hi(tp.x) + hi1 * bf_hi(tp.y)
            + hi2 * bf_hi(tp.z) + hi3 * bf_hi(tp.w);
    p = row16_allsum(p);
    q = row16_allsum(q);
    float a1 = fmaf(p, 0.5f, 0.5f);
    float a2 = fmaf(q, 0.5f, 0.5f);
    r1 += a1; r2 += a2;
    float v0 = bf_lo(ev.x), v1 = bf_hi(ev.x), v2 = bf_lo(ev.y), v3 = bf_hi(ev.y);
    s1.x = fmaf(a1, v0, s1.x); s1.y = fmaf(a1, v1, s1.y);
    s1.z = fmaf(a1, v2, s1.z); s1.w = fmaf(a1, v3, s1.w);
    s2.x = fmaf(a2, v0, s2.x); s2.y = fmaf(a2, v1, s2.y);
    s2.z = fmaf(a2, v2, s2.z); s2.w = fmaf(a2, v3, s2.w);
  }
#pragma unroll
  for (int m = 16; m <= 32; m <<= 1){
    s1.x += __shfl_xor(s1.x, m, 64); s1.y += __shfl_xor(s1.y, m, 64);
    s1.z += __shfl_xor(s1.z, m, 64); s1.w += __shfl_xor(s1.w, m, 64);
    s2.x += __shfl_xor(s2.x, m, 64); s2.y += __shfl_xor(s2.y, m, 64);
    s2.z += __shfl_xor(s2.z, m, 64); s2.w += __shfl_xor(s2.w, m, 64);
    r1   += __shfl_xor(r1,   m, 64); r2   += __shfl_xor(r2,   m, 64);
  }
  float d1 = (r1 > 0.f) ? 1.f / r1 : 0.f;
  float d2 = (r2 > 0.f) ? 1.f / r2 : 0.f;
  if (slot == 0){
    int idx4 = w * 16 + sub;
    float4 g = ((float4*)gnn_io)[idx4];
    uint2 it = inte_bf2[idx4];
    float4 em = ((const float4*)emb)[idx4];
    float4 nv;
    nv.x = g.x + bf_lo(it.x) + em.x + d1 * s1.x + d2 * s2.x;
    nv.y = g.y + bf_hi(it.x) + em.y + d1 * s1.y + d2 * s2.y;
    nv.z = g.z + bf_lo(it.y) + em.z + d1 * s1.z + d2 * s2.z;
    nv.w = g.w + bf_hi(it.y) + em.w + d1 * s1.w + d2 * s2.w;
    ((float4*)gnn_io)[idx4] = nv;
    float4 ac = ((float4*)acc)[idx4];
    ac.x += nv.x; ac.y += nv.y; ac.z += nv.z; ac.w += nv.w;
    ((float4*)acc)[idx4] = ac;
    uint2 ob;
    ob.x = (unsigned)f2bf(nv.x) | ((unsigned)f2bf(nv.y) << 16);
    ob.y = (unsigned)f2bf(nv.z) | ((unsigned)f2bf(nv.w) << 16);
    embb_next2[idx4] = ob;   // bf16 emb for next layer (other buffer: no race)
  }
}

extern "C" void kernel_launch(void* const* d_in, const int* in_sizes, int n_in,
                              void* d_out, int out_size, void* d_ws, size_t ws_size,
                              hipStream_t stream){
  const float* ue = (const float*)d_in[0];
  const float* ie = (const float*)d_in[1];
  const float* wu = (const float*)d_in[2];
  const float* wi = (const float*)d_in[3];
  const int* all_h = (const int*)d_in[4];
  const int* all_t = (const int*)d_in[5];
  float* acc = (float*)d_out;

  char* p = (char*)d_ws;
  auto take = [&](size_t bytes)->char*{
    char* r = p; p += (bytes + 255) & ~size_t(255); return r;
  };
  float*  embA  = (float*)take(sizeof(float) * N_NODES * DIM);
  float*  embB  = (float*)take(sizeof(float) * N_NODES * DIM);
  unsigned int* hgig = (unsigned int*)take(sizeof(unsigned int) * N_NODES * DIM);
  unsigned short* inte_bf = (unsigned short*)take(sizeof(short) * N_NODES * DIM);
  unsigned short* embbA   = (unsigned short*)take(sizeof(short) * N_NODES * DIM);
  unsigned short* embbB   = (unsigned short*)take(sizeof(short) * N_NODES * DIM);
  int*    t_csr = (int*)take(sizeof(int) * N_EDGES);
  float*  dis   = (float*)take(sizeof(float) * N_NODES);
  int*    deg   = (int*)take(sizeof(int) * N_NODES);
  int*    tmp   = (int*)take(sizeof(int) * N_NODES);
  int*    aux   = (int*)take(sizeof(int) * 1024);
  int*    rp    = (int*)take(sizeof(int) * (N_NODES + 1));
  int*    gcur  = (int*)take(sizeof(int) * NPART);
  if ((size_t)(p - (char*)d_ws) > ws_size) return;
  // staging (12 MB) aliases hgig (38.4 MB): only live before the layer loop
  unsigned int* stg = hgig;

  const int ELEM_B  = (N_NODES * DIM + 255) / 256;
  const int NODEW_B = (N_NODES * 64 + 255) / 256;
  const int EDGE_B  = (N_EDGES + 255) / 256;
  const int NODE_B  = (N_NODES + 255) / 256;

  hipMemsetAsync(deg, 0, sizeof(int) * N_NODES, stream);
  k_init<<<ELEM_B, 256, 0, stream>>>(ue, ie, embA, acc, embbA);
  k_deg<<<EDGE_B, 256, 0, stream>>>(all_h, deg);
  k_scan1<<<NODE_B, 256, 0, stream>>>(deg, tmp, aux);
  k_scan2<<<1, 1024, 0, stream>>>(aux, NODE_B);
  k_rowptr<<<NODE_B, 256, 0, stream>>>(tmp, deg, aux, rp, dis, gcur);
  k_part1<<<NCHB, 256, 0, stream>>>(all_h, all_t, gcur, stg);
  k_part2<<<NPART, 256, 0, stream>>>(rp, stg, t_csr);

  float* eA = embA;
  float* eB = embB;
  unsigned short* ebA = embbA;  // bf16 of current emb
  unsigned short* ebB = embbB;
  for (int layer = 0; layer < 2; layer++){
    k_spmm_gnn<<<NODEW_B, 256, 0, stream>>>(rp, t_csr, dis, (const uint2*)ebA,
                                            eB, (unsigned short*)hgig);
    k_intent<<<(N_USERS + 3) / 4, 256, 0, stream>>>(wu, eA, inte_bf,
                                                    (unsigned short*)hgig, 0, N_USERS);
    k_intent<<<(N_ITEMS + 3) / 4, 256, 0, stream>>>(wi, eA, inte_bf,
                                                    (unsigned short*)hgig, N_USERS, N_ITEMS);
    k_adafuse<<<NODEW_B, 256, 0, stream>>>(rp, t_csr, (const uint4*)hgig,
                                           (const uint2*)inte_bf, (const uint2*)ebA,
                                           eA, eB, acc, (uint2*)ebB);
    float* t = eA; eA = eB; eB = t;
    unsigned short* tb = ebA; ebA = ebB; ebB = tb;
  }
}